// Round 1
// baseline (1227.139 us; speedup 1.0000x reference)
//
#include <hip/hip_runtime.h>
#include <cstdint>
#include <cstddef>

#define N_NODES 50000
#define N_EDGES 500000
#define N_GRAPHS 256
#define D_IN 768
#define D_H1 256
#define D_H2 128
#define D_H3 64

// ---------------- degree histogram ----------------
__global__ void k_hist(const int* __restrict__ dst, int* __restrict__ deg, int n) {
    int e = blockIdx.x * blockDim.x + threadIdx.x;
    if (e < n) atomicAdd(&deg[dst[e]], 1);
}

// ---------------- exclusive scan over deg (single block) ----------------
__global__ void k_scan(const int* __restrict__ deg, int* __restrict__ row_start,
                       float* __restrict__ deg_inv, int n) {
    __shared__ int buf[1024];
    __shared__ int carry;
    int tid = threadIdx.x;
    if (tid == 0) carry = 0;
    __syncthreads();
    for (int base = 0; base < n; base += 1024) {
        int i = base + tid;
        int v = (i < n) ? deg[i] : 0;
        buf[tid] = v;
        __syncthreads();
        for (int off = 1; off < 1024; off <<= 1) {
            int t = (tid >= off) ? buf[tid - off] : 0;
            __syncthreads();
            buf[tid] += t;
            __syncthreads();
        }
        if (i < n) {
            row_start[i] = carry + buf[tid] - v;            // exclusive
            deg_inv[i] = (v > 0) ? (1.0f / (float)v) : 0.0f;
        }
        __syncthreads();
        if (tid == 0) carry += buf[1023];
        __syncthreads();
    }
    if (tid == 0) row_start[n] = carry;
}

// ---------------- CSR fill ----------------
__global__ void k_fill(const int* __restrict__ src, const int* __restrict__ dst,
                       const int* __restrict__ row_start, int* __restrict__ cursor,
                       int* __restrict__ csr_src, int n) {
    int e = blockIdx.x * blockDim.x + threadIdx.x;
    if (e < n) {
        int d = dst[e];
        int pos = row_start[d] + atomicAdd(&cursor[d], 1);
        csr_src[pos] = src[e];
    }
}

// ---------------- fp32 tiled GEMM: C[M,N] = A[M,K] @ W[N,K]^T (+add +bias +relu) ----
#define BM 64
#define BN 64
#define BK 16
#define LDT 68   // padded stride: float4-aligned, rotates banks by 4 per k-row

__global__ __launch_bounds__(256) void k_gemm(
    const float* __restrict__ A, const float* __restrict__ W,
    float* __restrict__ C, const float* __restrict__ addsrc,
    const float* __restrict__ bias, int M, int N, int K, int do_relu)
{
    __shared__ float As[BK * LDT];
    __shared__ float Ws[BK * LDT];
    int tid = threadIdx.x;
    int bm = blockIdx.x * BM;
    int bn = blockIdx.y * BN;
    int tn = tid & 15, tm = tid >> 4;   // 16x16 thread grid, each 4x4 outputs
    int lk4 = tid & 3, lr = tid >> 2;   // loader: k-quad, tile row

    float acc[4][4] = {};

    for (int k0 = 0; k0 < K; k0 += BK) {
        // stage A tile (transposed to [k][m]) and W tile ([k][n])
        {
            int row = bm + lr;
            float4 a = make_float4(0.f, 0.f, 0.f, 0.f);
            if (row < M) a = *(const float4*)&A[(size_t)row * K + k0 + lk4 * 4];
            As[(lk4 * 4 + 0) * LDT + lr] = a.x;
            As[(lk4 * 4 + 1) * LDT + lr] = a.y;
            As[(lk4 * 4 + 2) * LDT + lr] = a.z;
            As[(lk4 * 4 + 3) * LDT + lr] = a.w;
            int wrow = bn + lr;   // N is a multiple of 64 -> always in range
            float4 b = *(const float4*)&W[(size_t)wrow * K + k0 + lk4 * 4];
            Ws[(lk4 * 4 + 0) * LDT + lr] = b.x;
            Ws[(lk4 * 4 + 1) * LDT + lr] = b.y;
            Ws[(lk4 * 4 + 2) * LDT + lr] = b.z;
            Ws[(lk4 * 4 + 3) * LDT + lr] = b.w;
        }
        __syncthreads();
        #pragma unroll
        for (int kk = 0; kk < BK; ++kk) {
            float4 a = *(const float4*)&As[kk * LDT + tm * 4];
            float4 b = *(const float4*)&Ws[kk * LDT + tn * 4];
            float av[4] = {a.x, a.y, a.z, a.w};
            float bv[4] = {b.x, b.y, b.z, b.w};
            #pragma unroll
            for (int mi = 0; mi < 4; ++mi)
                #pragma unroll
                for (int ni = 0; ni < 4; ++ni)
                    acc[mi][ni] = fmaf(av[mi], bv[ni], acc[mi][ni]);
        }
        __syncthreads();
    }

    #pragma unroll
    for (int mi = 0; mi < 4; ++mi) {
        int r = bm + tm * 4 + mi;
        if (r >= M) continue;
        #pragma unroll
        for (int ni = 0; ni < 4; ++ni) {
            int c = bn + tn * 4 + ni;
            float v = acc[mi][ni];
            if (addsrc) v += addsrc[(size_t)r * N + c];
            if (bias) v += bias[c];
            if (do_relu) v = fmaxf(v, 0.f);
            C[(size_t)r * N + c] = v;
        }
    }
}

// ---------------- CSR gather mean-aggregate: out[i] = deg_inv[i]*sum_{j in N(i)} feat[j]
template <int D>
__global__ void k_aggregate(const float* __restrict__ feat, const int* __restrict__ row_start,
                            const int* __restrict__ csr_src, const float* __restrict__ deg_inv,
                            float* __restrict__ out)
{
    int node = blockIdx.x * (blockDim.x >> 6) + (threadIdx.x >> 6);  // wave per node
    if (node >= N_NODES) return;
    int lane = threadIdx.x & 63;
    int s = row_start[node], e = row_start[node + 1];
    constexpr int V = D / 64;  // 4 (D=256) or 2 (D=128)
    float acc[V] = {};
    for (int p = s; p < e; ++p) {
        int src = csr_src[p];
        const float* f = feat + (size_t)src * D + lane * V;
        if constexpr (V == 4) {
            float4 t = *(const float4*)f;
            acc[0] += t.x; acc[1] += t.y; acc[2] += t.z; acc[3] += t.w;
        } else {
            float2 t = *(const float2*)f;
            acc[0] += t.x; acc[1] += t.y;
        }
    }
    float w = deg_inv[node];
    float* o = out + (size_t)node * D + lane * V;
    #pragma unroll
    for (int v = 0; v < V; ++v) o[v] = acc[v] * w;
}

// ---------------- global mean pool (batch is sorted) ----------------
__global__ void k_pool(const float* __restrict__ h2, const int* __restrict__ batch,
                       float* __restrict__ pooled)
{
    int g = blockIdx.x;
    __shared__ int s_lo, s_hi;
    if (threadIdx.x == 0) {
        int lo = 0, hi = N_NODES;
        while (lo < hi) { int m = (lo + hi) >> 1; if (batch[m] < g) lo = m + 1; else hi = m; }
        s_lo = lo;
        int lo2 = lo, hi2 = N_NODES;
        while (lo2 < hi2) { int m = (lo2 + hi2) >> 1; if (batch[m] < g + 1) lo2 = m + 1; else hi2 = m; }
        s_hi = lo2;
    }
    __syncthreads();
    int dim = threadIdx.x;  // 128 threads, one per feature
    float sum = 0.f;
    for (int i = s_lo; i < s_hi; ++i) sum += h2[(size_t)i * D_H2 + dim];
    int cnt = s_hi - s_lo;
    pooled[g * D_H2 + dim] = sum / (float)(cnt > 0 ? cnt : 1);
}

// ---------------- head: (pooled@W3^T+b3)@W4^T+b4 -> softmax (no relu!) -----
__global__ void k_head(const float* __restrict__ pooled, const float* __restrict__ W3,
                       const float* __restrict__ b3, const float* __restrict__ W4,
                       const float* __restrict__ b4, float* __restrict__ out)
{
    int g = blockIdx.x;
    int j = threadIdx.x;  // 64
    __shared__ float p[128];
    __shared__ float hid[64];
    __shared__ float logit[2];
    p[j] = pooled[g * 128 + j];
    p[j + 64] = pooled[g * 128 + 64 + j];
    __syncthreads();
    float s = b3[j];
    #pragma unroll 4
    for (int k = 0; k < 128; ++k) s = fmaf(p[k], W3[j * 128 + k], s);
    hid[j] = s;
    __syncthreads();
    if (j < 2) {
        float l = b4[j];
        for (int k = 0; k < 64; ++k) l = fmaf(hid[k], W4[j * 64 + k], l);
        logit[j] = l;
    }
    __syncthreads();
    if (j == 0) {
        float m = fmaxf(logit[0], logit[1]);
        float e0 = expf(logit[0] - m), e1 = expf(logit[1] - m);
        float inv = 1.0f / (e0 + e1);
        out[g * 2 + 0] = e0 * inv;
        out[g * 2 + 1] = e1 * inv;
    }
}

extern "C" void kernel_launch(void* const* d_in, const int* in_sizes, int n_in,
                              void* d_out, int out_size, void* d_ws, size_t ws_size,
                              hipStream_t stream)
{
    const float* x     = (const float*)d_in[0];
    const int*   ei    = (const int*)d_in[1];
    const int*   batch = (const int*)d_in[2];
    const float* W1l   = (const float*)d_in[3];
    const float* b1l   = (const float*)d_in[4];
    const float* W1r   = (const float*)d_in[5];
    const float* W2l   = (const float*)d_in[6];
    const float* b2l   = (const float*)d_in[7];
    const float* W2r   = (const float*)d_in[8];
    const float* W3    = (const float*)d_in[9];
    const float* b3    = (const float*)d_in[10];
    const float* W4    = (const float*)d_in[11];
    const float* b4    = (const float*)d_in[12];
    float* out = (float*)d_out;

    const int* e_src = ei;
    const int* e_dst = ei + N_EDGES;

    char* ws = (char*)d_ws;
    size_t off = 0;
    auto alloc = [&](size_t bytes) -> void* {
        void* p = ws + off;
        off = (off + bytes + 255) & ~(size_t)255;
        return p;
    };
    int*   deg       = (int*)alloc((size_t)N_NODES * 4);
    int*   row_start = (int*)alloc((size_t)(N_NODES + 1) * 4);
    int*   cursor    = (int*)alloc((size_t)N_NODES * 4);
    int*   csr_src   = (int*)alloc((size_t)N_EDGES * 4);
    float* deg_inv   = (float*)alloc((size_t)N_NODES * 4);
    float* pooled    = (float*)alloc((size_t)N_GRAPHS * D_H2 * 4);
    float* bufA      = (float*)alloc((size_t)N_NODES * D_H1 * 4); // xl, then h1
    float* bufB      = (float*)alloc((size_t)N_NODES * D_H1 * 4); // aggr1, then {h1l, aggr2}
    float* bufC      = (float*)alloc((size_t)N_NODES * D_H2 * 4); // h2

    hipMemsetAsync(deg, 0, (size_t)N_NODES * 4, stream);
    hipMemsetAsync(cursor, 0, (size_t)N_NODES * 4, stream);

    // CSR build
    k_hist<<<(N_EDGES + 255) / 256, 256, 0, stream>>>(e_dst, deg, N_EDGES);
    k_scan<<<1, 1024, 0, stream>>>(deg, row_start, deg_inv, N_NODES);
    k_fill<<<(N_EDGES + 255) / 256, 256, 0, stream>>>(e_src, e_dst, row_start, cursor, csr_src, N_EDGES);

    // Layer 1 (project-first: aggregate in 256-d, not 768-d)
    dim3 g1((N_NODES + BM - 1) / BM, D_H1 / BN);
    k_gemm<<<g1, 256, 0, stream>>>(x, W1l, bufA, nullptr, nullptr, N_NODES, D_H1, D_IN, 0);      // xl
    k_aggregate<D_H1><<<(N_NODES + 3) / 4, 256, 0, stream>>>(bufA, row_start, csr_src, deg_inv, bufB);
    k_gemm<<<g1, 256, 0, stream>>>(x, W1r, bufA, bufB, b1l, N_NODES, D_H1, D_IN, 1);             // h1 = relu(x@W1r^T + aggr + b1)

    // Layer 2
    dim3 g2((N_NODES + BM - 1) / BM, D_H2 / BN);
    float* h1l   = bufB;
    float* aggr2 = bufB + (size_t)N_NODES * D_H2;
    k_gemm<<<g2, 256, 0, stream>>>(bufA, W2l, h1l, nullptr, nullptr, N_NODES, D_H2, D_H1, 0);
    k_aggregate<D_H2><<<(N_NODES + 3) / 4, 256, 0, stream>>>(h1l, row_start, csr_src, deg_inv, aggr2);
    k_gemm<<<g2, 256, 0, stream>>>(bufA, W2r, bufC, aggr2, b2l, N_NODES, D_H2, D_H1, 1);

    // Pool + head
    k_pool<<<N_GRAPHS, 128, 0, stream>>>(bufC, batch, pooled);
    k_head<<<N_GRAPHS, 64, 0, stream>>>(pooled, W3, b3, W4, b4, out);
}

// Round 2
// 697.740 us; speedup vs baseline: 1.7587x; 1.7587x over previous
//
#include <hip/hip_runtime.h>
#include <cstdint>
#include <cstddef>

#define N_NODES 50000
#define N_EDGES 500000
#define N_GRAPHS 256
#define D_IN 768
#define D_H1 256
#define D_H2 128
#define D_H3 64

typedef __attribute__((ext_vector_type(8))) __bf16 bf16x8;
typedef __attribute__((ext_vector_type(4))) float f32x4;

__device__ __forceinline__ float bf2f(uint16_t u) {
    union { uint32_t i; float f; } v; v.i = ((uint32_t)u) << 16; return v.f;
}
__device__ __forceinline__ uint16_t f2bf(float f) {
    union { float f; uint32_t i; } v; v.f = f;
    uint32_t u = v.i;
    uint32_t r = (u + 0x7FFFu + ((u >> 16) & 1u)) >> 16;
    return (uint16_t)r;
}
__device__ __forceinline__ void async16(const void* g, void* l) {
    __builtin_amdgcn_global_load_lds(
        (const __attribute__((address_space(1))) unsigned int*)g,
        (__attribute__((address_space(3))) unsigned int*)l, 16, 0, 0);
}

// ---------------- fp32 -> bf16 convert (4 elems/thread) ----------------
__global__ void k_cvt(const float* __restrict__ in, uint16_t* __restrict__ out, int n4) {
    int i = blockIdx.x * blockDim.x + threadIdx.x;
    if (i >= n4) return;
    float4 a = ((const float4*)in)[i];
    ushort4 o;
    o.x = f2bf(a.x); o.y = f2bf(a.y); o.z = f2bf(a.z); o.w = f2bf(a.w);
    ((ushort4*)out)[i] = o;
}

// ---------------- degree histogram ----------------
__global__ void k_hist(const int* __restrict__ dst, int* __restrict__ deg, int n) {
    int e = blockIdx.x * blockDim.x + threadIdx.x;
    if (e < n) atomicAdd(&deg[dst[e]], 1);
}

// ---------------- parallel exclusive scan (3 kernels) ----------------
__global__ void k_scan1(const int* __restrict__ deg, int* __restrict__ row_ex,
                        int* __restrict__ bsum, int n) {
    __shared__ int buf[256];
    int t = threadIdx.x, i = blockIdx.x * 256 + t;
    int v = (i < n) ? deg[i] : 0;
    buf[t] = v; __syncthreads();
    for (int off = 1; off < 256; off <<= 1) {
        int u = (t >= off) ? buf[t - off] : 0;
        __syncthreads(); buf[t] += u; __syncthreads();
    }
    if (i < n) row_ex[i] = buf[t] - v;
    if (t == 255) bsum[blockIdx.x] = buf[255];
}
__global__ void k_scan2(const int* __restrict__ bsum, int* __restrict__ boff, int nb) {
    __shared__ int buf[256];
    int t = threadIdx.x;
    int v = (t < nb) ? bsum[t] : 0;
    buf[t] = v; __syncthreads();
    for (int off = 1; off < 256; off <<= 1) {
        int u = (t >= off) ? buf[t - off] : 0;
        __syncthreads(); buf[t] += u; __syncthreads();
    }
    if (t < nb) boff[t] = buf[t] - v;
}
__global__ void k_scan3(const int* __restrict__ deg, const int* __restrict__ boff,
                        int* __restrict__ row_start, float* __restrict__ deg_inv, int n) {
    int i = blockIdx.x * 256 + threadIdx.x;
    if (i < n) {
        row_start[i] += boff[blockIdx.x];
        int d = deg[i];
        deg_inv[i] = (d > 0) ? (1.0f / (float)d) : 0.0f;
    }
    if (blockIdx.x == 0 && threadIdx.x == 0) row_start[n] = N_EDGES;
}

// ---------------- CSR fill ----------------
__global__ void k_fill(const int* __restrict__ src, const int* __restrict__ dst,
                       const int* __restrict__ row_start, int* __restrict__ cursor,
                       int* __restrict__ csr_src, int n) {
    int e = blockIdx.x * blockDim.x + threadIdx.x;
    if (e < n) {
        int d = dst[e];
        int pos = row_start[d] + atomicAdd(&cursor[d], 1);
        csr_src[pos] = src[e];
    }
}

// ---------------- bf16 MFMA GEMM (m97 structure): C[M,N] = A[M,K] @ W[N,K]^T ----
// A, W bf16 row-major (K contiguous). 128x128 block tile, BK=32, 4 waves 2x2,
// each wave 64x64 via 4x4 grid of 16x16x32 mfma. fp32 accum; epilogue
// +addsrc +bias +relu, output fp32 or bf16.
template <bool OUT_BF16>
__global__ __launch_bounds__(256) void k_mgemm(
    const uint16_t* __restrict__ A, const uint16_t* __restrict__ W,
    void* __restrict__ C, const float* __restrict__ addsrc,
    const float* __restrict__ bias, int M, int N, int K, int relu)
{
    __shared__ __bf16 As[128 * 32];
    __shared__ __bf16 Ws[128 * 32];
    const int tid = threadIdx.x;
    const int wave = tid >> 6, lane = tid & 63;
    const int bm = blockIdx.x * 128, bn = blockIdx.y * 128;
    const int wm = (wave >> 1) * 64, wn = (wave & 1) * 64;

    // staging: wave w stages rows [w*32, w*32+32) of both tiles, 2 instrs of 16 rows
    const int srow = (lane >> 2);          // row within 16-row group
    const int skoff = (lane & 3) * 8;      // k element offset (16B chunks)
    // fragment indices
    const int fr = lane & 15, fq = lane >> 4;

    f32x4 acc[4][4] = {};

    for (int k0 = 0; k0 < K; k0 += 32) {
        #pragma unroll
        for (int j = 0; j < 2; ++j) {
            int rbase = wave * 32 + j * 16;
            int ga = bm + rbase + srow; if (ga >= M) ga = M - 1;   // clamp, discarded later
            async16(A + (size_t)ga * K + k0 + skoff, &As[rbase * 32]);
            int gw = bn + rbase + srow;                            // N % 128 == 0
            async16(W + (size_t)gw * K + k0 + skoff, &Ws[rbase * 32]);
        }
        __syncthreads();
        bf16x8 af[4], bfv[4];
        #pragma unroll
        for (int mi = 0; mi < 4; ++mi)
            af[mi] = *(const bf16x8*)&As[(wm + mi * 16 + fr) * 32 + fq * 8];
        #pragma unroll
        for (int ni = 0; ni < 4; ++ni)
            bfv[ni] = *(const bf16x8*)&Ws[(wn + ni * 16 + fr) * 32 + fq * 8];
        #pragma unroll
        for (int mi = 0; mi < 4; ++mi)
            #pragma unroll
            for (int ni = 0; ni < 4; ++ni)
                acc[mi][ni] = __builtin_amdgcn_mfma_f32_16x16x32_bf16(
                    af[mi], bfv[ni], acc[mi][ni], 0, 0, 0);
        __syncthreads();
    }

    #pragma unroll
    for (int mi = 0; mi < 4; ++mi) {
        #pragma unroll
        for (int r = 0; r < 4; ++r) {
            int row = bm + wm + mi * 16 + fq * 4 + r;
            if (row >= M) continue;
            #pragma unroll
            for (int ni = 0; ni < 4; ++ni) {
                int col = bn + wn + ni * 16 + fr;
                float v = acc[mi][ni][r];
                if (addsrc) v += addsrc[(size_t)row * N + col];
                if (bias) v += bias[col];
                if (relu) v = fmaxf(v, 0.f);
                if (OUT_BF16) ((uint16_t*)C)[(size_t)row * N + col] = f2bf(v);
                else          ((float*)C)[(size_t)row * N + col] = v;
            }
        }
    }
}

// ---------------- CSR gather mean-aggregate over bf16 features -> fp32 out ----
template <int D>
__global__ void k_aggregate(const uint16_t* __restrict__ feat, const int* __restrict__ row_start,
                            const int* __restrict__ csr_src, const float* __restrict__ deg_inv,
                            float* __restrict__ out)
{
    int node = blockIdx.x * (blockDim.x >> 6) + (threadIdx.x >> 6);  // wave per node
    if (node >= N_NODES) return;
    int lane = threadIdx.x & 63;
    int s = row_start[node], e = row_start[node + 1];
    constexpr int V = D / 64;  // 4 (D=256) or 2 (D=128) bf16 per lane
    float acc[V] = {};
    for (int p = s; p < e; ++p) {
        int src = csr_src[p];
        const uint16_t* f = feat + (size_t)src * D + lane * V;
        if constexpr (V == 4) {
            uint2 t = *(const uint2*)f;
            acc[0] += bf2f((uint16_t)(t.x & 0xFFFF));
            acc[1] += bf2f((uint16_t)(t.x >> 16));
            acc[2] += bf2f((uint16_t)(t.y & 0xFFFF));
            acc[3] += bf2f((uint16_t)(t.y >> 16));
        } else {
            uint32_t t = *(const uint32_t*)f;
            acc[0] += bf2f((uint16_t)(t & 0xFFFF));
            acc[1] += bf2f((uint16_t)(t >> 16));
        }
    }
    float w = deg_inv[node];
    float* o = out + (size_t)node * D + lane * V;
    #pragma unroll
    for (int v = 0; v < V; ++v) o[v] = acc[v] * w;
}

// ---------------- global mean pool (batch is sorted) ----------------
__global__ void k_pool(const float* __restrict__ h2, const int* __restrict__ batch,
                       float* __restrict__ pooled)
{
    int g = blockIdx.x;
    __shared__ int s_lo, s_hi;
    if (threadIdx.x == 0) {
        int lo = 0, hi = N_NODES;
        while (lo < hi) { int m = (lo + hi) >> 1; if (batch[m] < g) lo = m + 1; else hi = m; }
        s_lo = lo;
        int lo2 = lo, hi2 = N_NODES;
        while (lo2 < hi2) { int m = (lo2 + hi2) >> 1; if (batch[m] < g + 1) lo2 = m + 1; else hi2 = m; }
        s_hi = lo2;
    }
    __syncthreads();
    int dim = threadIdx.x;  // 128 threads, one per feature
    float sum = 0.f;
    for (int i = s_lo; i < s_hi; ++i) sum += h2[(size_t)i * D_H2 + dim];
    int cnt = s_hi - s_lo;
    pooled[g * D_H2 + dim] = sum / (float)(cnt > 0 ? cnt : 1);
}

// ---------------- head: (pooled@W3^T+b3)@W4^T+b4 -> softmax (no relu) -----
__global__ void k_head(const float* __restrict__ pooled, const float* __restrict__ W3,
                       const float* __restrict__ b3, const float* __restrict__ W4,
                       const float* __restrict__ b4, float* __restrict__ out)
{
    int g = blockIdx.x;
    int j = threadIdx.x;  // 64
    __shared__ float p[128];
    __shared__ float hid[64];
    __shared__ float logit[2];
    p[j] = pooled[g * 128 + j];
    p[j + 64] = pooled[g * 128 + 64 + j];
    __syncthreads();
    float s = b3[j];
    #pragma unroll 4
    for (int k = 0; k < 128; ++k) s = fmaf(p[k], W3[j * 128 + k], s);
    hid[j] = s;
    __syncthreads();
    if (j < 2) {
        float l = b4[j];
        for (int k = 0; k < 64; ++k) l = fmaf(hid[k], W4[j * 64 + k], l);
        logit[j] = l;
    }
    __syncthreads();
    if (j == 0) {
        float m = fmaxf(logit[0], logit[1]);
        float e0 = expf(logit[0] - m), e1 = expf(logit[1] - m);
        float inv = 1.0f / (e0 + e1);
        out[g * 2 + 0] = e0 * inv;
        out[g * 2 + 1] = e1 * inv;
    }
}

extern "C" void kernel_launch(void* const* d_in, const int* in_sizes, int n_in,
                              void* d_out, int out_size, void* d_ws, size_t ws_size,
                              hipStream_t stream)
{
    const float* x     = (const float*)d_in[0];
    const int*   ei    = (const int*)d_in[1];
    const int*   batch = (const int*)d_in[2];
    const float* W1l   = (const float*)d_in[3];
    const float* b1l   = (const float*)d_in[4];
    const float* W1r   = (const float*)d_in[5];
    const float* W2l   = (const float*)d_in[6];
    const float* b2l   = (const float*)d_in[7];
    const float* W2r   = (const float*)d_in[8];
    const float* W3    = (const float*)d_in[9];
    const float* b3    = (const float*)d_in[10];
    const float* W4    = (const float*)d_in[11];
    const float* b4    = (const float*)d_in[12];
    float* out = (float*)d_out;

    const int* e_src = ei;
    const int* e_dst = ei + N_EDGES;

    char* ws = (char*)d_ws;
    size_t off = 0;
    auto alloc = [&](size_t bytes) -> void* {
        void* p = ws + off;
        off = (off + bytes + 255) & ~(size_t)255;
        return p;
    };
    int*      deg       = (int*)alloc((size_t)N_NODES * 4);
    int*      row_start = (int*)alloc((size_t)(N_NODES + 1) * 4);
    int*      cursor    = (int*)alloc((size_t)N_NODES * 4);
    int*      csr_src   = (int*)alloc((size_t)N_EDGES * 4);
    float*    deg_inv   = (float*)alloc((size_t)N_NODES * 4);
    int*      bsum      = (int*)alloc(256 * 4);
    int*      boff      = (int*)alloc(256 * 4);
    float*    pooled    = (float*)alloc((size_t)N_GRAPHS * D_H2 * 4);
    uint16_t* w1lb      = (uint16_t*)alloc((size_t)D_H1 * D_IN * 2);
    uint16_t* w1rb      = (uint16_t*)alloc((size_t)D_H1 * D_IN * 2);
    uint16_t* w2lb      = (uint16_t*)alloc((size_t)D_H2 * D_H1 * 2);
    uint16_t* w2rb      = (uint16_t*)alloc((size_t)D_H2 * D_H1 * 2);
    uint16_t* xb        = (uint16_t*)alloc((size_t)N_NODES * D_IN * 2);   // 76.8 MB; reused as h2 (f32, 25.6 MB)
    uint16_t* bufA      = (uint16_t*)alloc((size_t)N_NODES * D_H1 * 2);   // xl bf16, then h1 bf16
    float*    bufB      = (float*)alloc((size_t)N_NODES * D_H1 * 4);      // aggr1 f32, then {h1l bf16, aggr2 f32}

    float*    h2    = (float*)xb;                                  // alias: xb dead after GEMM1r
    uint16_t* h1lb  = (uint16_t*)bufB;                             // 12.8 MB
    float*    aggr2 = (float*)((char*)bufB + (size_t)N_NODES * D_H2 * 2 + 256); // after h1lb

    hipMemsetAsync(deg, 0, (size_t)N_NODES * 4, stream);
    hipMemsetAsync(cursor, 0, (size_t)N_NODES * 4, stream);

    // ---- CSR build ----
    k_hist<<<(N_EDGES + 255) / 256, 256, 0, stream>>>(e_dst, deg, N_EDGES);
    int nscan = (N_NODES + 255) / 256;  // 196
    k_scan1<<<nscan, 256, 0, stream>>>(deg, row_start, bsum, N_NODES);
    k_scan2<<<1, 256, 0, stream>>>(bsum, boff, nscan);
    k_scan3<<<nscan, 256, 0, stream>>>(deg, boff, row_start, deg_inv, N_NODES);
    k_fill<<<(N_EDGES + 255) / 256, 256, 0, stream>>>(e_src, e_dst, row_start, cursor, csr_src, N_EDGES);

    // ---- bf16 conversions ----
    k_cvt<<<((N_NODES * D_IN / 4) + 255) / 256, 256, 0, stream>>>(x, xb, N_NODES * D_IN / 4);
    k_cvt<<<((D_H1 * D_IN / 4) + 255) / 256, 256, 0, stream>>>(W1l, w1lb, D_H1 * D_IN / 4);
    k_cvt<<<((D_H1 * D_IN / 4) + 255) / 256, 256, 0, stream>>>(W1r, w1rb, D_H1 * D_IN / 4);
    k_cvt<<<((D_H2 * D_H1 / 4) + 255) / 256, 256, 0, stream>>>(W2l, w2lb, D_H2 * D_H1 / 4);
    k_cvt<<<((D_H2 * D_H1 / 4) + 255) / 256, 256, 0, stream>>>(W2r, w2rb, D_H2 * D_H1 / 4);

    // ---- Layer 1 (project-first: aggregate in 256-d) ----
    dim3 g1((N_NODES + 127) / 128, D_H1 / 128);
    k_mgemm<true><<<g1, 256, 0, stream>>>(xb, w1lb, bufA, nullptr, nullptr, N_NODES, D_H1, D_IN, 0);  // xl bf16
    k_aggregate<D_H1><<<(N_NODES + 3) / 4, 256, 0, stream>>>(bufA, row_start, csr_src, deg_inv, bufB);
    k_mgemm<true><<<g1, 256, 0, stream>>>(xb, w1rb, bufA, bufB, b1l, N_NODES, D_H1, D_IN, 1);         // h1 bf16

    // ---- Layer 2 ----
    dim3 g2((N_NODES + 127) / 128, D_H2 / 128);
    k_mgemm<true><<<g2, 256, 0, stream>>>(bufA, w2lb, h1lb, nullptr, nullptr, N_NODES, D_H2, D_H1, 0); // h1l bf16
    k_aggregate<D_H2><<<(N_NODES + 3) / 4, 256, 0, stream>>>(h1lb, row_start, csr_src, deg_inv, aggr2);
    k_mgemm<false><<<g2, 256, 0, stream>>>(bufA, w2rb, h2, aggr2, b2l, N_NODES, D_H2, D_H1, 1);        // h2 f32

    // ---- Pool + head ----
    k_pool<<<N_GRAPHS, 128, 0, stream>>>(h2, batch, pooled);
    k_head<<<N_GRAPHS, 64, 0, stream>>>(pooled, W3, b3, W4, b4, out);
}

// Round 3
// 662.399 us; speedup vs baseline: 1.8526x; 1.0534x over previous
//
#include <hip/hip_runtime.h>
#include <cstdint>
#include <cstddef>

#define N_NODES 50000
#define N_EDGES 500000
#define N_GRAPHS 256
#define D_IN 768
#define D_H1 256
#define D_H2 128

typedef __attribute__((ext_vector_type(8))) __bf16 bf16x8;
typedef __attribute__((ext_vector_type(4))) float f32x4;

__device__ __forceinline__ float bf2f(uint32_t u) {
    union { uint32_t i; float f; } v; v.i = u << 16; return v.f;
}
__device__ __forceinline__ uint16_t f2bf(float f) {
    union { float f; uint32_t i; } v; v.f = f;
    uint32_t u = v.i;
    return (uint16_t)((u + 0x7FFFu + ((u >> 16) & 1u)) >> 16);
}

// ---------------- fp32 -> bf16 convert (4 elems/thread) ----------------
__global__ void k_cvt(const float* __restrict__ in, uint16_t* __restrict__ out, int n4) {
    int i = blockIdx.x * blockDim.x + threadIdx.x;
    if (i >= n4) return;
    float4 a = ((const float4*)in)[i];
    ushort4 o;
    o.x = f2bf(a.x); o.y = f2bf(a.y); o.z = f2bf(a.z); o.w = f2bf(a.w);
    ((ushort4*)out)[i] = o;
}

// ---------------- degree histogram ----------------
__global__ void k_hist(const int* __restrict__ dst, int* __restrict__ deg, int n) {
    int e = blockIdx.x * blockDim.x + threadIdx.x;
    if (e < n) atomicAdd(&deg[dst[e]], 1);
}

// ---------------- parallel exclusive scan (3 kernels) ----------------
__global__ void k_scan1(const int* __restrict__ deg, int* __restrict__ row_ex,
                        int* __restrict__ bsum, int n) {
    __shared__ int buf[256];
    int t = threadIdx.x, i = blockIdx.x * 256 + t;
    int v = (i < n) ? deg[i] : 0;
    buf[t] = v; __syncthreads();
    for (int off = 1; off < 256; off <<= 1) {
        int u = (t >= off) ? buf[t - off] : 0;
        __syncthreads(); buf[t] += u; __syncthreads();
    }
    if (i < n) row_ex[i] = buf[t] - v;
    if (t == 255) bsum[blockIdx.x] = buf[255];
}
__global__ void k_scan2(const int* __restrict__ bsum, int* __restrict__ boff, int nb) {
    __shared__ int buf[256];
    int t = threadIdx.x;
    int v = (t < nb) ? bsum[t] : 0;
    buf[t] = v; __syncthreads();
    for (int off = 1; off < 256; off <<= 1) {
        int u = (t >= off) ? buf[t - off] : 0;
        __syncthreads(); buf[t] += u; __syncthreads();
    }
    if (t < nb) boff[t] = buf[t] - v;
}
__global__ void k_scan3(const int* __restrict__ deg, const int* __restrict__ boff,
                        int* __restrict__ row_start, float* __restrict__ deg_inv, int n) {
    int i = blockIdx.x * 256 + threadIdx.x;
    if (i < n) {
        row_start[i] += boff[blockIdx.x];
        int d = deg[i];
        deg_inv[i] = (d > 0) ? (1.0f / (float)d) : 0.0f;
    }
    if (blockIdx.x == 0 && threadIdx.x == 0) row_start[n] = N_EDGES;
}

// ---------------- CSR fill ----------------
__global__ void k_fill(const int* __restrict__ src, const int* __restrict__ dst,
                       const int* __restrict__ row_start, int* __restrict__ cursor,
                       int* __restrict__ csr_src, int n) {
    int e = blockIdx.x * blockDim.x + threadIdx.x;
    if (e < n) {
        int d = dst[e];
        int pos = row_start[d] + atomicAdd(&cursor[d], 1);
        csr_src[pos] = src[e];
    }
}

// ---------------- barrier-free direct-global MFMA GEMM ----------------
// C[M,N] = A[M,K] @ B[N,K]^T, all bf16, fp32 accum, bf16 out.
// Block 128M x 256N, 4 waves 2x2, wave tile 64M x 128N.
// No LDS, no __syncthreads: each wave streams its own fragments from global
// with a depth-2 register ping-pong so the compiler emits fine-grained
// vmcnt waits (loads for step k+1 in flight during MFMA of step k).
__global__ __launch_bounds__(256, 2) void k_mgemm(
    const uint16_t* __restrict__ A, const uint16_t* __restrict__ B,
    uint16_t* __restrict__ C, int M, int N, int K)
{
    const int tid = threadIdx.x;
    const int wave = tid >> 6, lane = tid & 63;
    const int fr = lane & 15, fq = lane >> 4;
    const int bn = blockIdx.x * 256, bm = blockIdx.y * 128;   // N fastest-varying
    const int wm = (wave >> 1) * 64, wn = (wave & 1) * 128;

    int aOff[4], bOff[8];   // element offsets (k added per step)
    #pragma unroll
    for (int mi = 0; mi < 4; ++mi) {
        int r = bm + wm + mi * 16 + fr;
        if (r > M - 1) r = M - 1;           // clamp; rows >= M discarded at store
        aOff[mi] = r * K + fq * 8;
    }
    #pragma unroll
    for (int ni = 0; ni < 8; ++ni) {
        int r = bn + wn + ni * 16 + fr;     // N is multiple of 256
        bOff[ni] = r * K + fq * 8;
    }

    f32x4 acc[4][8] = {};
    bf16x8 a0[4], b0[8], a1[4], b1[8];

    auto lA = [&](int k, bf16x8* d) {
        #pragma unroll
        for (int mi = 0; mi < 4; ++mi) d[mi] = *(const bf16x8*)(A + aOff[mi] + k);
    };
    auto lB = [&](int k, bf16x8* d) {
        #pragma unroll
        for (int ni = 0; ni < 8; ++ni) d[ni] = *(const bf16x8*)(B + bOff[ni] + k);
    };
    auto step = [&](bf16x8* a, bf16x8* b) {
        #pragma unroll
        for (int mi = 0; mi < 4; ++mi)
            #pragma unroll
            for (int ni = 0; ni < 8; ++ni)
                acc[mi][ni] = __builtin_amdgcn_mfma_f32_16x16x32_bf16(
                    a[mi], b[ni], acc[mi][ni], 0, 0, 0);
    };

    lA(0, a0); lB(0, b0);
    const int KS = K >> 5;                  // K/32; 24 (L1) or 8 (L2), both even
    for (int ks = 0; ks < KS; ks += 2) {
        lA((ks + 1) << 5, a1); lB((ks + 1) << 5, b1);
        step(a0, b0);
        if (ks + 2 < KS) { lA((ks + 2) << 5, a0); lB((ks + 2) << 5, b0); }
        step(a1, b1);
    }

    #pragma unroll
    for (int mi = 0; mi < 4; ++mi) {
        #pragma unroll
        for (int r = 0; r < 4; ++r) {
            int row = bm + wm + mi * 16 + fq * 4 + r;
            if (row >= M) continue;
            #pragma unroll
            for (int ni = 0; ni < 8; ++ni) {
                int col = bn + wn + ni * 16 + fr;
                C[(size_t)row * N + col] = f2bf(acc[mi][ni][r]);
            }
        }
    }
}

// ---- fused aggregate layer1: h1 = relu(deg_inv*sum(y1[nbr,0:256]) + y1[node,256:512] + b1)
__global__ __launch_bounds__(256) void k_agg1(
    const uint16_t* __restrict__ y, const int* __restrict__ row_start,
    const int* __restrict__ csr, const float* __restrict__ deg_inv,
    const float* __restrict__ bias, uint16_t* __restrict__ out)
{
    int node = blockIdx.x * 4 + (threadIdx.x >> 6);
    if (node >= N_NODES) return;
    int lane = threadIdx.x & 63;
    int s = row_start[node], e = row_start[node + 1];
    float a0 = 0.f, a1 = 0.f, a2 = 0.f, a3 = 0.f;
    int p = s;
    for (; p + 1 < e; p += 2) {
        uint2 t0 = *(const uint2*)(y + (size_t)csr[p] * 512 + lane * 4);
        uint2 t1 = *(const uint2*)(y + (size_t)csr[p + 1] * 512 + lane * 4);
        a0 += bf2f(t0.x & 0xFFFF) + bf2f(t1.x & 0xFFFF);
        a1 += bf2f(t0.x >> 16)    + bf2f(t1.x >> 16);
        a2 += bf2f(t0.y & 0xFFFF) + bf2f(t1.y & 0xFFFF);
        a3 += bf2f(t0.y >> 16)    + bf2f(t1.y >> 16);
    }
    if (p < e) {
        uint2 t0 = *(const uint2*)(y + (size_t)csr[p] * 512 + lane * 4);
        a0 += bf2f(t0.x & 0xFFFF);
        a1 += bf2f(t0.x >> 16);
        a2 += bf2f(t0.y & 0xFFFF);
        a3 += bf2f(t0.y >> 16);
    }
    float w = deg_inv[node];
    uint2 tx = *(const uint2*)(y + (size_t)node * 512 + 256 + lane * 4);
    float4 b = *(const float4*)(bias + lane * 4);
    float v0 = fmaxf(a0 * w + bf2f(tx.x & 0xFFFF) + b.x, 0.f);
    float v1 = fmaxf(a1 * w + bf2f(tx.x >> 16)    + b.y, 0.f);
    float v2 = fmaxf(a2 * w + bf2f(tx.y & 0xFFFF) + b.z, 0.f);
    float v3 = fmaxf(a3 * w + bf2f(tx.y >> 16)    + b.w, 0.f);
    ushort4 o; o.x = f2bf(v0); o.y = f2bf(v1); o.z = f2bf(v2); o.w = f2bf(v3);
    *(ushort4*)(out + (size_t)node * 256 + lane * 4) = o;
}

// ---- fused aggregate layer2: h2 = relu(deg_inv*sum(y2[nbr,0:128]) + y2[node,128:256] + b2), f32 out
__global__ __launch_bounds__(256) void k_agg2(
    const uint16_t* __restrict__ y, const int* __restrict__ row_start,
    const int* __restrict__ csr, const float* __restrict__ deg_inv,
    const float* __restrict__ bias, float* __restrict__ out)
{
    int node = blockIdx.x * 4 + (threadIdx.x >> 6);
    if (node >= N_NODES) return;
    int lane = threadIdx.x & 63;
    int s = row_start[node], e = row_start[node + 1];
    float a0 = 0.f, a1 = 0.f;
    int p = s;
    for (; p + 1 < e; p += 2) {
        uint32_t t0 = *(const uint32_t*)(y + (size_t)csr[p] * 256 + lane * 2);
        uint32_t t1 = *(const uint32_t*)(y + (size_t)csr[p + 1] * 256 + lane * 2);
        a0 += bf2f(t0 & 0xFFFF) + bf2f(t1 & 0xFFFF);
        a1 += bf2f(t0 >> 16)    + bf2f(t1 >> 16);
    }
    if (p < e) {
        uint32_t t0 = *(const uint32_t*)(y + (size_t)csr[p] * 256 + lane * 2);
        a0 += bf2f(t0 & 0xFFFF);
        a1 += bf2f(t0 >> 16);
    }
    float w = deg_inv[node];
    uint32_t tx = *(const uint32_t*)(y + (size_t)node * 256 + 128 + lane * 2);
    float2 b = *(const float2*)(bias + lane * 2);
    float2 o;
    o.x = fmaxf(a0 * w + bf2f(tx & 0xFFFF) + b.x, 0.f);
    o.y = fmaxf(a1 * w + bf2f(tx >> 16)    + b.y, 0.f);
    *(float2*)(out + (size_t)node * 128 + lane * 2) = o;
}

// ---------------- global mean pool (batch is sorted) ----------------
__global__ void k_pool(const float* __restrict__ h2, const int* __restrict__ batch,
                       float* __restrict__ pooled)
{
    int g = blockIdx.x;
    __shared__ int s_lo, s_hi;
    if (threadIdx.x == 0) {
        int lo = 0, hi = N_NODES;
        while (lo < hi) { int m = (lo + hi) >> 1; if (batch[m] < g) lo = m + 1; else hi = m; }
        s_lo = lo;
        int lo2 = lo, hi2 = N_NODES;
        while (lo2 < hi2) { int m = (lo2 + hi2) >> 1; if (batch[m] < g + 1) lo2 = m + 1; else hi2 = m; }
        s_hi = lo2;
    }
    __syncthreads();
    int dim = threadIdx.x;  // 128 threads
    float sum = 0.f;
    for (int i = s_lo; i < s_hi; ++i) sum += h2[(size_t)i * D_H2 + dim];
    int cnt = s_hi - s_lo;
    pooled[g * D_H2 + dim] = sum / (float)(cnt > 0 ? cnt : 1);
}

// ---------------- head: (pooled@W3^T+b3)@W4^T+b4 -> softmax (no relu) -----
__global__ void k_head(const float* __restrict__ pooled, const float* __restrict__ W3,
                       const float* __restrict__ b3, const float* __restrict__ W4,
                       const float* __restrict__ b4, float* __restrict__ out)
{
    int g = blockIdx.x;
    int j = threadIdx.x;  // 64
    __shared__ float p[128];
    __shared__ float hid[64];
    __shared__ float logit[2];
    p[j] = pooled[g * 128 + j];
    p[j + 64] = pooled[g * 128 + 64 + j];
    __syncthreads();
    float s = b3[j];
    #pragma unroll 4
    for (int k = 0; k < 128; ++k) s = fmaf(p[k], W3[j * 128 + k], s);
    hid[j] = s;
    __syncthreads();
    if (j < 2) {
        float l = b4[j];
        for (int k = 0; k < 64; ++k) l = fmaf(hid[k], W4[j * 64 + k], l);
        logit[j] = l;
    }
    __syncthreads();
    if (j == 0) {
        float m = fmaxf(logit[0], logit[1]);
        float e0 = expf(logit[0] - m), e1 = expf(logit[1] - m);
        float inv = 1.0f / (e0 + e1);
        out[g * 2 + 0] = e0 * inv;
        out[g * 2 + 1] = e1 * inv;
    }
}

extern "C" void kernel_launch(void* const* d_in, const int* in_sizes, int n_in,
                              void* d_out, int out_size, void* d_ws, size_t ws_size,
                              hipStream_t stream)
{
    const float* x     = (const float*)d_in[0];
    const int*   ei    = (const int*)d_in[1];
    const int*   batch = (const int*)d_in[2];
    const float* W1l   = (const float*)d_in[3];
    const float* b1l   = (const float*)d_in[4];
    const float* W1r   = (const float*)d_in[5];
    const float* W2l   = (const float*)d_in[6];
    const float* b2l   = (const float*)d_in[7];
    const float* W2r   = (const float*)d_in[8];
    const float* W3    = (const float*)d_in[9];
    const float* b3    = (const float*)d_in[10];
    const float* W4    = (const float*)d_in[11];
    const float* b4    = (const float*)d_in[12];
    float* out = (float*)d_out;

    const int* e_src = ei;
    const int* e_dst = ei + N_EDGES;

    char* ws = (char*)d_ws;
    size_t off = 0;
    auto alloc = [&](size_t bytes) -> void* {
        void* p = ws + off;
        off = (off + bytes + 255) & ~(size_t)255;
        return p;
    };
    int*      deg       = (int*)alloc((size_t)N_NODES * 4);
    int*      row_start = (int*)alloc((size_t)(N_NODES + 1) * 4);
    int*      cursor    = (int*)alloc((size_t)N_NODES * 4);
    int*      csr_src   = (int*)alloc((size_t)N_EDGES * 4);
    float*    deg_inv   = (float*)alloc((size_t)N_NODES * 4);
    int*      bsum      = (int*)alloc(256 * 4);
    int*      boff      = (int*)alloc(256 * 4);
    float*    pooled    = (float*)alloc((size_t)N_GRAPHS * D_H2 * 4);
    uint16_t* W1cat     = (uint16_t*)alloc((size_t)512 * 768 * 2);  // rows 0:256 = W1l, 256:512 = W1r
    uint16_t* W2cat     = (uint16_t*)alloc((size_t)256 * 256 * 2);  // rows 0:128 = W2l, 128:256 = W2r
    uint16_t* xb        = (uint16_t*)alloc((size_t)N_NODES * D_IN * 2);  // 76.8 MB; dead after GEMM1
    uint16_t* y1        = (uint16_t*)alloc((size_t)N_NODES * 512 * 2);   // 51.2 MB [xl | xr]
    uint16_t* h1        = (uint16_t*)alloc((size_t)N_NODES * 256 * 2);   // 25.6 MB

    uint16_t* y2 = xb;                                        // [h1l | h1r], 25.6 MB
    float*    h2 = (float*)(xb + (size_t)N_NODES * 256);      // f32, 25.6 MB (xb region holds both)

    hipMemsetAsync(deg, 0, (size_t)N_NODES * 4, stream);
    hipMemsetAsync(cursor, 0, (size_t)N_NODES * 4, stream);

    // ---- CSR build ----
    k_hist<<<(N_EDGES + 255) / 256, 256, 0, stream>>>(e_dst, deg, N_EDGES);
    int nscan = (N_NODES + 255) / 256;  // 196
    k_scan1<<<nscan, 256, 0, stream>>>(deg, row_start, bsum, N_NODES);
    k_scan2<<<1, 256, 0, stream>>>(bsum, boff, nscan);
    k_scan3<<<nscan, 256, 0, stream>>>(deg, boff, row_start, deg_inv, N_NODES);
    k_fill<<<(N_EDGES + 255) / 256, 256, 0, stream>>>(e_src, e_dst, row_start, cursor, csr_src, N_EDGES);

    // ---- bf16 conversions (weights concatenated) ----
    k_cvt<<<((N_NODES * D_IN / 4) + 255) / 256, 256, 0, stream>>>(x, xb, N_NODES * D_IN / 4);
    k_cvt<<<((256 * 768 / 4) + 255) / 256, 256, 0, stream>>>(W1l, W1cat, 256 * 768 / 4);
    k_cvt<<<((256 * 768 / 4) + 255) / 256, 256, 0, stream>>>(W1r, W1cat + (size_t)256 * 768, 256 * 768 / 4);
    k_cvt<<<((128 * 256 / 4) + 255) / 256, 256, 0, stream>>>(W2l, W2cat, 128 * 256 / 4);
    k_cvt<<<((128 * 256 / 4) + 255) / 256, 256, 0, stream>>>(W2r, W2cat + (size_t)128 * 256, 128 * 256 / 4);

    // ---- Layer 1: y1 = xb @ [W1l|W1r]^T  (N=512 fused) ----
    dim3 g1(512 / 256, (N_NODES + 127) / 128);   // N fastest -> A-stripe reuse
    k_mgemm<<<g1, 256, 0, stream>>>(xb, W1cat, y1, N_NODES, 512, 768);
    k_agg1<<<(N_NODES + 3) / 4, 256, 0, stream>>>(y1, row_start, csr_src, deg_inv, b1l, h1);

    // ---- Layer 2: y2 = h1 @ [W2l|W2r]^T  (N=256 fused) ----
    dim3 g2(1, (N_NODES + 127) / 128);
    k_mgemm<<<g2, 256, 0, stream>>>(h1, W2cat, y2, N_NODES, 256, 256);
    k_agg2<<<(N_NODES + 3) / 4, 256, 0, stream>>>(y2, row_start, csr_src, deg_inv, b2l, h2);

    // ---- Pool + head ----
    k_pool<<<N_GRAPHS, 128, 0, stream>>>(h2, batch, pooled);
    k_head<<<N_GRAPHS, 64, 0, stream>>>(pooled, W3, b3, W4, b4, out);
}

// Round 4
// 529.693 us; speedup vs baseline: 2.3167x; 1.2505x over previous
//
#include <hip/hip_runtime.h>
#include <cstdint>
#include <cstddef>

#define N_NODES 50000
#define N_EDGES 500000
#define N_GRAPHS 256
#define D_IN 768
#define D_H1 256
#define D_H2 128

typedef __attribute__((ext_vector_type(8))) __bf16 bf16x8;
typedef __attribute__((ext_vector_type(4))) float f32x4;

__device__ __forceinline__ float bf2f(uint32_t u) {
    union { uint32_t i; float f; } v; v.i = u << 16; return v.f;
}
__device__ __forceinline__ uint32_t f2bf(float f) {
    union { float f; uint32_t i; } v; v.f = f;
    uint32_t u = v.i;
    return (u + 0x7FFFu + ((u >> 16) & 1u)) >> 16;
}

// ---- pack fp32 [rows][K] row-major -> bf16 MFMA fragment tiles ----
// chunk c = ((mt*KT + kt)*64 + lane), lane = fq*16+fr holds
// A[mt*16+fr][kt*32+fq*8 .. +7] as 16 bytes. One thread per chunk.
__global__ void k_packA(const float* __restrict__ in, uint16_t* __restrict__ out,
                        int nchunks, int KT, int K) {
    int c = blockIdx.x * 256 + threadIdx.x;
    if (c >= nchunks) return;
    int l = c & 63, t = c >> 6;
    int kt = t % KT, mt = t / KT;
    int fr = l & 15, fq = l >> 4;
    const float* p = in + (size_t)(mt * 16 + fr) * K + kt * 32 + fq * 8;
    float4 u = *(const float4*)p, v = *(const float4*)(p + 4);
    uint4 o;
    o.x = f2bf(u.x) | (f2bf(u.y) << 16);
    o.y = f2bf(u.z) | (f2bf(u.w) << 16);
    o.z = f2bf(v.x) | (f2bf(v.y) << 16);
    o.w = f2bf(v.z) | (f2bf(v.w) << 16);
    *(uint4*)(out + (size_t)c * 8) = o;
}

// same, but rows come from two stacked matrices [rowsL|rowsR]
__global__ void k_packW(const float* __restrict__ inL, const float* __restrict__ inR,
                        uint16_t* __restrict__ out, int rowsL, int nchunks, int KT, int K) {
    int c = blockIdx.x * 256 + threadIdx.x;
    if (c >= nchunks) return;
    int l = c & 63, t = c >> 6;
    int kt = t % KT, mt = t / KT;
    int fr = l & 15, fq = l >> 4;
    int row = mt * 16 + fr;
    const float* src = (row < rowsL) ? (inL + (size_t)row * K) : (inR + (size_t)(row - rowsL) * K);
    const float* p = src + kt * 32 + fq * 8;
    float4 u = *(const float4*)p, v = *(const float4*)(p + 4);
    uint4 o;
    o.x = f2bf(u.x) | (f2bf(u.y) << 16);
    o.y = f2bf(u.z) | (f2bf(u.w) << 16);
    o.z = f2bf(v.x) | (f2bf(v.y) << 16);
    o.w = f2bf(v.z) | (f2bf(v.w) << 16);
    *(uint4*)(out + (size_t)c * 8) = o;
}

// ---------------- degree histogram ----------------
__global__ void k_hist(const int* __restrict__ dst, int* __restrict__ deg, int n) {
    int e = blockIdx.x * blockDim.x + threadIdx.x;
    if (e < n) atomicAdd(&deg[dst[e]], 1);
}

// ---------------- parallel exclusive scan (3 kernels) ----------------
__global__ void k_scan1(const int* __restrict__ deg, int* __restrict__ row_ex,
                        int* __restrict__ bsum, int n) {
    __shared__ int buf[256];
    int t = threadIdx.x, i = blockIdx.x * 256 + t;
    int v = (i < n) ? deg[i] : 0;
    buf[t] = v; __syncthreads();
    for (int off = 1; off < 256; off <<= 1) {
        int u = (t >= off) ? buf[t - off] : 0;
        __syncthreads(); buf[t] += u; __syncthreads();
    }
    if (i < n) row_ex[i] = buf[t] - v;
    if (t == 255) bsum[blockIdx.x] = buf[255];
}
__global__ void k_scan2(const int* __restrict__ bsum, int* __restrict__ boff, int nb) {
    __shared__ int buf[256];
    int t = threadIdx.x;
    int v = (t < nb) ? bsum[t] : 0;
    buf[t] = v; __syncthreads();
    for (int off = 1; off < 256; off <<= 1) {
        int u = (t >= off) ? buf[t - off] : 0;
        __syncthreads(); buf[t] += u; __syncthreads();
    }
    if (t < nb) boff[t] = buf[t] - v;
}
__global__ void k_scan3(const int* __restrict__ deg, const int* __restrict__ boff,
                        int* __restrict__ row_start, float* __restrict__ deg_inv, int n) {
    int i = blockIdx.x * 256 + threadIdx.x;
    if (i < n) {
        row_start[i] += boff[blockIdx.x];
        int d = deg[i];
        deg_inv[i] = (d > 0) ? (1.0f / (float)d) : 0.0f;
    }
    if (blockIdx.x == 0 && threadIdx.x == 0) row_start[n] = N_EDGES;
}

// ---------------- CSR fill ----------------
__global__ void k_fill(const int* __restrict__ src, const int* __restrict__ dst,
                       const int* __restrict__ row_start, int* __restrict__ cursor,
                       int* __restrict__ csr_src, int n) {
    int e = blockIdx.x * blockDim.x + threadIdx.x;
    if (e < n) {
        int d = dst[e];
        int pos = row_start[d] + atomicAdd(&cursor[d], 1);
        csr_src[pos] = src[e];
    }
}

// ---------------- barrier-free MFMA GEMM on fragment-packed operands ----------
// C[M,N] = A[M,K] @ B[N,K]^T ; Ap/Bp in packed-tile layout (see k_packA).
// Block 128M x 256N, 4 waves 2x2 (wave 64x128). Every fragment load is a
// fully coalesced 1KB global_load_dwordx4 burst; depth-2 register ping-pong,
// no LDS, no barriers.
__global__ __launch_bounds__(256, 2) void k_mgemm(
    const uint16_t* __restrict__ Ap, const uint16_t* __restrict__ Bp,
    uint16_t* __restrict__ C, int M, int N, int KT)
{
    const int tid = threadIdx.x;
    const int wave = tid >> 6, lane = tid & 63;
    const int fr = lane & 15, fq = lane >> 4;
    const int bn = blockIdx.x * 256, bm = blockIdx.y * 128;
    const int wm = (wave >> 1) * 64, wn = (wave & 1) * 128;
    const int mtiles = (M + 15) >> 4;

    const bf16x8* ap[4];
    const bf16x8* bp[8];
    #pragma unroll
    for (int mi = 0; mi < 4; ++mi) {
        int mt = ((bm + wm) >> 4) + mi;
        if (mt > mtiles - 1) mt = mtiles - 1;   // tail block: duplicate tile, store masked
        ap[mi] = (const bf16x8*)Ap + (size_t)mt * KT * 64 + lane;
    }
    #pragma unroll
    for (int ni = 0; ni < 8; ++ni) {
        int nt = ((bn + wn) >> 4) + ni;         // N multiple of 256
        bp[ni] = (const bf16x8*)Bp + (size_t)nt * KT * 64 + lane;
    }

    f32x4 acc[4][8] = {};
    bf16x8 a0[4], b0[8], a1[4], b1[8];

    auto lA = [&](int kt, bf16x8* d) {
        #pragma unroll
        for (int mi = 0; mi < 4; ++mi) d[mi] = ap[mi][kt * 64];
    };
    auto lB = [&](int kt, bf16x8* d) {
        #pragma unroll
        for (int ni = 0; ni < 8; ++ni) d[ni] = bp[ni][kt * 64];
    };
    auto step = [&](bf16x8* a, bf16x8* b) {
        #pragma unroll
        for (int mi = 0; mi < 4; ++mi)
            #pragma unroll
            for (int ni = 0; ni < 8; ++ni)
                acc[mi][ni] = __builtin_amdgcn_mfma_f32_16x16x32_bf16(
                    a[mi], b[ni], acc[mi][ni], 0, 0, 0);
    };

    lA(0, a0); lB(0, b0);
    for (int ks = 0; ks < KT; ks += 2) {        // KT even (24 or 8)
        lA(ks + 1, a1); lB(ks + 1, b1);
        step(a0, b0);
        if (ks + 2 < KT) { lA(ks + 2, a0); lB(ks + 2, b0); }
        step(a1, b1);
    }

    #pragma unroll
    for (int mi = 0; mi < 4; ++mi) {
        #pragma unroll
        for (int r = 0; r < 4; ++r) {
            int row = bm + wm + mi * 16 + fq * 4 + r;
            if (row >= M) continue;
            #pragma unroll
            for (int ni = 0; ni < 8; ++ni) {
                int col = bn + wn + ni * 16 + fr;
                C[(size_t)row * N + col] = (uint16_t)f2bf(acc[mi][ni][r]);
            }
        }
    }
}

// ---- fused aggregate layer1 -> packed h1 ----
// h1 = relu(deg_inv*sum(y1[nbr,0:256]) + y1[node,256:512] + b1), written in
// MFMA packed-tile layout for GEMM2. Half-wave (32 lanes) per node, 8 dims/lane.
__global__ __launch_bounds__(256) void k_agg1(
    const uint16_t* __restrict__ y, const int* __restrict__ row_start,
    const int* __restrict__ csr, const float* __restrict__ deg_inv,
    const float* __restrict__ bias, uint16_t* __restrict__ h1p)
{
    int node = blockIdx.x * 8 + (threadIdx.x >> 5);
    if (node >= N_NODES) return;
    int c = threadIdx.x & 31;                    // dim chunk: dims c*8 .. c*8+7
    int s = row_start[node], e = row_start[node + 1];
    float a[8] = {};
    int p = s;
    for (; p + 1 < e; p += 2) {
        uint4 t0 = *(const uint4*)(y + (size_t)csr[p] * 512 + c * 8);
        uint4 t1 = *(const uint4*)(y + (size_t)csr[p + 1] * 512 + c * 8);
        a[0] += bf2f(t0.x & 0xFFFF) + bf2f(t1.x & 0xFFFF);
        a[1] += bf2f(t0.x >> 16)    + bf2f(t1.x >> 16);
        a[2] += bf2f(t0.y & 0xFFFF) + bf2f(t1.y & 0xFFFF);
        a[3] += bf2f(t0.y >> 16)    + bf2f(t1.y >> 16);
        a[4] += bf2f(t0.z & 0xFFFF) + bf2f(t1.z & 0xFFFF);
        a[5] += bf2f(t0.z >> 16)    + bf2f(t1.z >> 16);
        a[6] += bf2f(t0.w & 0xFFFF) + bf2f(t1.w & 0xFFFF);
        a[7] += bf2f(t0.w >> 16)    + bf2f(t1.w >> 16);
    }
    if (p < e) {
        uint4 t0 = *(const uint4*)(y + (size_t)csr[p] * 512 + c * 8);
        a[0] += bf2f(t0.x & 0xFFFF); a[1] += bf2f(t0.x >> 16);
        a[2] += bf2f(t0.y & 0xFFFF); a[3] += bf2f(t0.y >> 16);
        a[4] += bf2f(t0.z & 0xFFFF); a[5] += bf2f(t0.z >> 16);
        a[6] += bf2f(t0.w & 0xFFFF); a[7] += bf2f(t0.w >> 16);
    }
    float w = deg_inv[node];
    uint4 tx = *(const uint4*)(y + (size_t)node * 512 + 256 + c * 8);
    float4 b0 = *(const float4*)(bias + c * 8);
    float4 b1 = *(const float4*)(bias + c * 8 + 4);
    float v0 = fmaxf(a[0] * w + bf2f(tx.x & 0xFFFF) + b0.x, 0.f);
    float v1 = fmaxf(a[1] * w + bf2f(tx.x >> 16)    + b0.y, 0.f);
    float v2 = fmaxf(a[2] * w + bf2f(tx.y & 0xFFFF) + b0.z, 0.f);
    float v3 = fmaxf(a[3] * w + bf2f(tx.y >> 16)    + b0.w, 0.f);
    float v4 = fmaxf(a[4] * w + bf2f(tx.z & 0xFFFF) + b1.x, 0.f);
    float v5 = fmaxf(a[5] * w + bf2f(tx.z >> 16)    + b1.y, 0.f);
    float v6 = fmaxf(a[6] * w + bf2f(tx.w & 0xFFFF) + b1.z, 0.f);
    float v7 = fmaxf(a[7] * w + bf2f(tx.w >> 16)    + b1.w, 0.f);
    uint4 o;
    o.x = f2bf(v0) | (f2bf(v1) << 16);
    o.y = f2bf(v2) | (f2bf(v3) << 16);
    o.z = f2bf(v4) | (f2bf(v5) << 16);
    o.w = f2bf(v6) | (f2bf(v7) << 16);
    // packed chunk: mt=node/16, fr=node%16, kt=c/4, fq=c%4
    uint32_t addr = (((node >> 4) * 8 + (c >> 2)) * 64 + (c & 3) * 16 + (node & 15));
    *(uint4*)(h1p + (size_t)addr * 8) = o;
}

// ---- fused aggregate layer2: h2 = relu(deg_inv*sum(y2[nbr,0:128]) + y2[node,128:256] + b2), f32 out
__global__ __launch_bounds__(256) void k_agg2(
    const uint16_t* __restrict__ y, const int* __restrict__ row_start,
    const int* __restrict__ csr, const float* __restrict__ deg_inv,
    const float* __restrict__ bias, float* __restrict__ out)
{
    int node = blockIdx.x * 4 + (threadIdx.x >> 6);
    if (node >= N_NODES) return;
    int lane = threadIdx.x & 63;
    int s = row_start[node], e = row_start[node + 1];
    float a0 = 0.f, a1 = 0.f;
    int p = s;
    for (; p + 1 < e; p += 2) {
        uint32_t t0 = *(const uint32_t*)(y + (size_t)csr[p] * 256 + lane * 2);
        uint32_t t1 = *(const uint32_t*)(y + (size_t)csr[p + 1] * 256 + lane * 2);
        a0 += bf2f(t0 & 0xFFFF) + bf2f(t1 & 0xFFFF);
        a1 += bf2f(t0 >> 16)    + bf2f(t1 >> 16);
    }
    if (p < e) {
        uint32_t t0 = *(const uint32_t*)(y + (size_t)csr[p] * 256 + lane * 2);
        a0 += bf2f(t0 & 0xFFFF);
        a1 += bf2f(t0 >> 16);
    }
    float w = deg_inv[node];
    uint32_t tx = *(const uint32_t*)(y + (size_t)node * 256 + 128 + lane * 2);
    float2 b = *(const float2*)(bias + lane * 2);
    float2 o;
    o.x = fmaxf(a0 * w + bf2f(tx & 0xFFFF) + b.x, 0.f);
    o.y = fmaxf(a1 * w + bf2f(tx >> 16)    + b.y, 0.f);
    *(float2*)(out + (size_t)node * 128 + lane * 2) = o;
}

// ---------------- global mean pool (batch is sorted) ----------------
__global__ void k_pool(const float* __restrict__ h2, const int* __restrict__ batch,
                       float* __restrict__ pooled)
{
    int g = blockIdx.x;
    __shared__ int s_lo, s_hi;
    if (threadIdx.x == 0) {
        int lo = 0, hi = N_NODES;
        while (lo < hi) { int m = (lo + hi) >> 1; if (batch[m] < g) lo = m + 1; else hi = m; }
        s_lo = lo;
        int lo2 = lo, hi2 = N_NODES;
        while (lo2 < hi2) { int m = (lo2 + hi2) >> 1; if (batch[m] < g + 1) lo2 = m + 1; else hi2 = m; }
        s_hi = lo2;
    }
    __syncthreads();
    int dim = threadIdx.x;  // 128 threads
    float sum = 0.f;
    for (int i = s_lo; i < s_hi; ++i) sum += h2[(size_t)i * D_H2 + dim];
    int cnt = s_hi - s_lo;
    pooled[g * D_H2 + dim] = sum / (float)(cnt > 0 ? cnt : 1);
}

// ---------------- head: (pooled@W3^T+b3)@W4^T+b4 -> softmax (no relu) -----
__global__ void k_head(const float* __restrict__ pooled, const float* __restrict__ W3,
                       const float* __restrict__ b3, const float* __restrict__ W4,
                       const float* __restrict__ b4, float* __restrict__ out)
{
    int g = blockIdx.x;
    int j = threadIdx.x;  // 64
    __shared__ float p[128];
    __shared__ float hid[64];
    __shared__ float logit[2];
    p[j] = pooled[g * 128 + j];
    p[j + 64] = pooled[g * 128 + 64 + j];
    __syncthreads();
    float s = b3[j];
    #pragma unroll 4
    for (int k = 0; k < 128; ++k) s = fmaf(p[k], W3[j * 128 + k], s);
    hid[j] = s;
    __syncthreads();
    if (j < 2) {
        float l = b4[j];
        for (int k = 0; k < 64; ++k) l = fmaf(hid[k], W4[j * 64 + k], l);
        logit[j] = l;
    }
    __syncthreads();
    if (j == 0) {
        float m = fmaxf(logit[0], logit[1]);
        float e0 = expf(logit[0] - m), e1 = expf(logit[1] - m);
        float inv = 1.0f / (e0 + e1);
        out[g * 2 + 0] = e0 * inv;
        out[g * 2 + 1] = e1 * inv;
    }
}

extern "C" void kernel_launch(void* const* d_in, const int* in_sizes, int n_in,
                              void* d_out, int out_size, void* d_ws, size_t ws_size,
                              hipStream_t stream)
{
    const float* x     = (const float*)d_in[0];
    const int*   ei    = (const int*)d_in[1];
    const int*   batch = (const int*)d_in[2];
    const float* W1l   = (const float*)d_in[3];
    const float* b1l   = (const float*)d_in[4];
    const float* W1r   = (const float*)d_in[5];
    const float* W2l   = (const float*)d_in[6];
    const float* b2l   = (const float*)d_in[7];
    const float* W2r   = (const float*)d_in[8];
    const float* W3    = (const float*)d_in[9];
    const float* b3    = (const float*)d_in[10];
    const float* W4    = (const float*)d_in[11];
    const float* b4    = (const float*)d_in[12];
    float* out = (float*)d_out;

    const int* e_src = ei;
    const int* e_dst = ei + N_EDGES;

    char* ws = (char*)d_ws;
    size_t off = 0;
    auto alloc = [&](size_t bytes) -> void* {
        void* p = ws + off;
        off = (off + bytes + 255) & ~(size_t)255;
        return p;
    };
    int*      deg       = (int*)alloc((size_t)N_NODES * 4);
    int*      row_start = (int*)alloc((size_t)(N_NODES + 1) * 4);
    int*      cursor    = (int*)alloc((size_t)N_NODES * 4);
    int*      csr_src   = (int*)alloc((size_t)N_EDGES * 4);
    float*    deg_inv   = (float*)alloc((size_t)N_NODES * 4);
    int*      bsum      = (int*)alloc(256 * 4);
    int*      boff      = (int*)alloc(256 * 4);
    float*    pooled    = (float*)alloc((size_t)N_GRAPHS * D_H2 * 4);
    uint16_t* W1p       = (uint16_t*)alloc((size_t)512 * 768 * 2);       // packed [W1l|W1r]
    uint16_t* W2p       = (uint16_t*)alloc((size_t)256 * 256 * 2);       // packed [W2l|W2r]
    uint16_t* xp        = (uint16_t*)alloc((size_t)N_NODES * D_IN * 2);  // packed x, 76.8 MB; reused later
    uint16_t* y1        = (uint16_t*)alloc((size_t)N_NODES * 512 * 2);   // 51.2 MB row-major
    uint16_t* h1p       = (uint16_t*)alloc((size_t)N_NODES * 256 * 2);   // packed h1, 25.6 MB

    uint16_t* y2 = xp;                                       // [h1l|h1r] row-major, 25.6 MB
    float*    h2 = (float*)(xp + (size_t)N_NODES * 256);     // f32, 25.6 MB (fits in xp region)

    hipMemsetAsync(deg, 0, (size_t)N_NODES * 4, stream);
    hipMemsetAsync(cursor, 0, (size_t)N_NODES * 4, stream);

    // ---- CSR build ----
    k_hist<<<(N_EDGES + 255) / 256, 256, 0, stream>>>(e_dst, deg, N_EDGES);
    int nscan = (N_NODES + 255) / 256;
    k_scan1<<<nscan, 256, 0, stream>>>(deg, row_start, bsum, N_NODES);
    k_scan2<<<1, 256, 0, stream>>>(bsum, boff, nscan);
    k_scan3<<<nscan, 256, 0, stream>>>(deg, boff, row_start, deg_inv, N_NODES);
    k_fill<<<(N_EDGES + 255) / 256, 256, 0, stream>>>(e_src, e_dst, row_start, cursor, csr_src, N_EDGES);

    // ---- pack operands (fp32 -> bf16 fragment tiles) ----
    int ncA = 3125 * 24 * 64;                       // x: 3125 m-tiles, 24 k-tiles
    k_packA<<<(ncA + 255) / 256, 256, 0, stream>>>(x, xp, ncA, 24, 768);
    int ncW1 = 32 * 24 * 64;                        // 512 rows
    k_packW<<<(ncW1 + 255) / 256, 256, 0, stream>>>(W1l, W1r, W1p, 256, ncW1, 24, 768);
    int ncW2 = 16 * 8 * 64;                         // 256 rows
    k_packW<<<(ncW2 + 255) / 256, 256, 0, stream>>>(W2l, W2r, W2p, 128, ncW2, 8, 256);

    // ---- Layer 1: y1 = x @ [W1l|W1r]^T  (M=50000, N=512, K=768) ----
    dim3 g1(2, (N_NODES + 127) / 128);
    k_mgemm<<<g1, 256, 0, stream>>>(xp, W1p, y1, N_NODES, 512, 24);
    k_agg1<<<(N_NODES + 7) / 8, 256, 0, stream>>>(y1, row_start, csr_src, deg_inv, b1l, h1p);

    // ---- Layer 2: y2 = h1 @ [W2l|W2r]^T  (M=50000, N=256, K=256) ----
    dim3 g2(1, (N_NODES + 127) / 128);
    k_mgemm<<<g2, 256, 0, stream>>>(h1p, W2p, y2, N_NODES, 256, 8);
    k_agg2<<<(N_NODES + 3) / 4, 256, 0, stream>>>(y2, row_start, csr_src, deg_inv, b2l, h2);

    // ---- Pool + head ----
    k_pool<<<N_GRAPHS, 128, 0, stream>>>(h2, batch, pooled);
    k_head<<<N_GRAPHS, 64, 0, stream>>>(pooled, W3, b3, W4, b4, out);
}